// Round 3
// baseline (668.546 us; speedup 1.0000x reference)
//
#include <hip/hip_runtime.h>
#include <math.h>

#define NN  100000
#define NE  3200000
#define FIN 512
#define HID 256
#define NC  40

#define NBUK 391                      // ceil(NN/256), bucket = row>>8
#define SPB  9472                     // fixed slots per bucket (mean 8184 + 14 sigma)
#define BIN_BLOCKS 512
#define CHUNK ((NE + BIN_BLOCKS - 1) / BIN_BLOCKS)   // 6250
#define COLMASK 0x1FFFF

typedef __attribute__((ext_vector_type(8))) short short8;
typedef __attribute__((ext_vector_type(4))) float f32x4;

__device__ inline float bf2f(unsigned short u) {
    unsigned int x = ((unsigned int)u) << 16;
    return __builtin_bit_cast(float, x);
}
__device__ inline unsigned short f2bfu(float f) {
    unsigned int x = __builtin_bit_cast(unsigned int, f);
    unsigned int r = (x + 0x7fffu + ((x >> 16) & 1u)) >> 16;
    return (unsigned short)r;
}
__device__ inline signed char q8(float v, float s) {
    int q = (int)rintf(v * s);
    q = max(-127, min(127, q));
    return (signed char)q;
}
__device__ inline unsigned cvtpk_bf16(float lo, float hi) {
    unsigned r;
    asm("v_cvt_pk_bf16_f32 %0, %1, %2" : "=v"(r) : "v"(lo), "v"(hi));
    return r;
}
// single-instruction unsigned-byte -> float converts (V_CVT_F32_UBYTE0..3)
__device__ inline float cub0(int r) { float f; asm("v_cvt_f32_ubyte0 %0, %1" : "=v"(f) : "v"(r)); return f; }
__device__ inline float cub1(int r) { float f; asm("v_cvt_f32_ubyte1 %0, %1" : "=v"(f) : "v"(r)); return f; }
__device__ inline float cub2(int r) { float f; asm("v_cvt_f32_ubyte2 %0, %1" : "=v"(f) : "v"(r)); return f; }
__device__ inline float cub3(int r) { float f; asm("v_cvt_f32_ubyte3 %0, %1" : "=v"(f) : "v"(r)); return f; }

// ---------------- bin edges into fixed-stride bucket staging (no pre-scan) ----------------
__global__ __launch_bounds__(256) void k_bin(const int* __restrict__ er, const int* __restrict__ ec,
                                             const float* __restrict__ ev, int* __restrict__ bcnt,
                                             int2* __restrict__ spack) {
    __shared__ int hist[NBUK];
    __shared__ int base[NBUK];
    __shared__ int lcur[NBUK];
    for (int i = threadIdx.x; i < NBUK; i += 256) { hist[i] = 0; lcur[i] = 0; }
    __syncthreads();
    int start = blockIdx.x * CHUNK;
    int end = min(start + CHUNK, NE);
    for (int e = start + threadIdx.x; e < end; e += 256)
        atomicAdd(&hist[er[e] >> 8], 1);
    __syncthreads();
    for (int i = threadIdx.x; i < NBUK; i += 256) {
        int h = hist[i];
        base[i] = h ? atomicAdd(&bcnt[i], h) : 0;
    }
    __syncthreads();
    for (int e = start + threadIdx.x; e < end; e += 256) {
        int r = er[e];
        int b = r >> 8;
        int ofs = atomicAdd(&lcur[b], 1);
        int2 p;
        p.x = ((r & 255) << 17) | ec[e];
        p.y = __builtin_bit_cast(int, ev[e]);
        spack[(size_t)b * SPB + base[b] + ofs] = p;
    }
}

// ---------------- fine CSR within each bucket ----------------
__global__ __launch_bounds__(256) void k_finecsr(const int2* __restrict__ spack, const int* __restrict__ bcnt,
                                                 int2* __restrict__ cpack,
                                                 int* __restrict__ row_beg, int* __restrict__ row_cnt) {
    __shared__ int cnt[256];
    __shared__ int sm[256];
    __shared__ int cur[256];
    int tid = threadIdx.x;
    int buk = blockIdx.x;
    size_t bb = (size_t)buk * SPB;
    int n = min(bcnt[buk], SPB);
    cnt[tid] = 0;
    __syncthreads();
    for (int i = tid; i < n; i += 256) {
        int lr = ((unsigned)spack[bb + i].x) >> 17;
        atomicAdd(&cnt[lr], 1);
    }
    __syncthreads();
    int v = cnt[tid];
    sm[tid] = v;
    __syncthreads();
    for (int off = 1; off < 256; off <<= 1) {
        int t = (tid >= off) ? sm[tid - off] : 0;
        __syncthreads();
        sm[tid] += t;
        __syncthreads();
    }
    int ex = sm[tid] - v;
    cur[tid] = ex;
    int grow = buk * 256 + tid;
    if (grow < NN) {
        row_beg[grow] = (int)bb + ex;
        row_cnt[grow] = v;
    }
    __syncthreads();
    for (int i = tid; i < n; i += 256) {
        int2 p = spack[bb + i];
        int lr = ((unsigned)p.x) >> 17;
        int pos = atomicAdd(&cur[lr], 1);
        int2 q;
        q.x = p.x & COLMASK;
        q.y = p.y;
        cpack[bb + pos] = q;
    }
}

// ---------------- W1 -> bf16 transposed [HID][FIN] ----------------
__global__ __launch_bounds__(256) void k_w1t(const float* __restrict__ W1, unsigned short* __restrict__ W1T) {
    int b = blockIdx.x;     // 32 blocks, 16 k each
    int n = threadIdx.x;
    unsigned short tmp[16];
#pragma unroll
    for (int kk = 0; kk < 16; kk++)
        tmp[kk] = f2bfu(W1[(size_t)(b * 16 + kk) * HID + n]);
    unsigned short* dst = W1T + (size_t)n * FIN + b * 16;
    *(short8*)dst = *(short8*)tmp;
    *(short8*)(dst + 8) = *(short8*)(tmp + 8);
}

// ---------------- W2 -> bf16 transposed [48][HID] (cols >= NC zero) ----------------
__global__ __launch_bounds__(256) void k_w2t(const float* __restrict__ W2, unsigned short* __restrict__ W2T) {
    int n = blockIdx.x;      // 0..47
    int k = threadIdx.x;     // 0..255
    float v = (n < NC) ? W2[(size_t)k * NC + n] : 0.f;
    W2T[(size_t)n * HID + k] = f2bfu(v);
}

// ---------------- GEMM1: h1 = u8( bf16(x) @ W1T , scale 16, +128 bias ) ----------------
// 128x128 tile (grid 782 x 2 over N=256), 4 waves 2x2, wave 64x64 acc[4][4].
// Double-buffered LDS (80 B row stride -> 2-way bank alias = free), one barrier
// per K-step; global loads for tile t+2 issued while tile t computes.
__global__ __launch_bounds__(256) void k_gemm1(const float* __restrict__ x, const unsigned short* __restrict__ W1T,
                                               unsigned char* __restrict__ h1) {
    __shared__ unsigned short As[2][128][40];
    __shared__ unsigned short Bs[2][128][40];
    const int tid = threadIdx.x;
    const int row0 = (blockIdx.x >> 1) * 128;
    const int col0 = (blockIdx.x & 1) * 128;
    const int lane = tid & 63;
    const int w = tid >> 6;
    const int wr = (w >> 1) * 64;
    const int wc = (w & 1) * 64;
    const int m16 = lane & 15;
    const int quad = lane >> 4;

    // staging: thread t covers row tid>>1, k-halves (tid&1)*16 .. +16
    const int srow = tid >> 1;
    const int skoff = (tid & 1) * 16;
    int gar = row0 + srow;
    if (gar >= NN) gar = NN - 1;
    const float* ax = x + (size_t)gar * FIN + skoff;
    const unsigned short* bw = W1T + (size_t)(col0 + srow) * FIN + skoff;

    f32x4 acc[4][4];
#pragma unroll
    for (int i = 0; i < 4; i++)
#pragma unroll
        for (int j = 0; j < 4; j++) acc[i][j] = (f32x4){0.f, 0.f, 0.f, 0.f};

    float4 va[4];
    uint4 vb0, vb1;

#define G1_LOAD(tt)                                                        \
    {                                                                      \
        const float* ap = ax + (tt) * 32;                                  \
        va[0] = *(const float4*)(ap);                                      \
        va[1] = *(const float4*)(ap + 4);                                  \
        va[2] = *(const float4*)(ap + 8);                                  \
        va[3] = *(const float4*)(ap + 12);                                 \
        const unsigned short* bp = bw + (tt) * 32;                         \
        vb0 = *(const uint4*)(bp);                                         \
        vb1 = *(const uint4*)(bp + 8);                                     \
    }

#define G1_STORE(bf)                                                       \
    {                                                                      \
        uint4 pa0, pa1;                                                    \
        pa0.x = cvtpk_bf16(va[0].x, va[0].y);                              \
        pa0.y = cvtpk_bf16(va[0].z, va[0].w);                              \
        pa0.z = cvtpk_bf16(va[1].x, va[1].y);                              \
        pa0.w = cvtpk_bf16(va[1].z, va[1].w);                              \
        pa1.x = cvtpk_bf16(va[2].x, va[2].y);                              \
        pa1.y = cvtpk_bf16(va[2].z, va[2].w);                              \
        pa1.z = cvtpk_bf16(va[3].x, va[3].y);                              \
        pa1.w = cvtpk_bf16(va[3].z, va[3].w);                              \
        *(uint4*)(&As[bf][srow][skoff]) = pa0;                             \
        *(uint4*)(&As[bf][srow][skoff + 8]) = pa1;                         \
        *(uint4*)(&Bs[bf][srow][skoff]) = vb0;                             \
        *(uint4*)(&Bs[bf][srow][skoff + 8]) = vb1;                         \
    }

    // prologue: tile 0 staged, tile 1 in regs
    G1_LOAD(0)
    G1_STORE(0)
    G1_LOAD(1)
    __syncthreads();

    for (int t = 0; t < 16; ++t) {
        const int buf = t & 1;
        short8 af[4], bfr[4];
#pragma unroll
        for (int i = 0; i < 4; i++) af[i] = *(const short8*)(&As[buf][wr + i * 16 + m16][quad * 8]);
#pragma unroll
        for (int j = 0; j < 4; j++) bfr[j] = *(const short8*)(&Bs[buf][wc + j * 16 + m16][quad * 8]);
        if (t < 15) {
            G1_STORE(buf ^ 1)          // consumes regs of tile t+1 (vmcnt wait inserted)
            if (t < 14) G1_LOAD(t + 2) // issue tile t+2, hides under MFMA + next iter
        }
#pragma unroll
        for (int i = 0; i < 4; i++)
#pragma unroll
            for (int j = 0; j < 4; j++)
                acc[i][j] = __builtin_amdgcn_mfma_f32_16x16x32_bf16(af[i], bfr[j], acc[i][j], 0, 0, 0);
        __syncthreads();
    }
#undef G1_LOAD
#undef G1_STORE

    // epilogue: C/D layout col=lane&15, row=quad*4+reg; quantize to u8 = int8(scale16)+128
#pragma unroll
    for (int i = 0; i < 4; i++) {
#pragma unroll
        for (int r = 0; r < 4; r++) {
            int gr = row0 + wr + i * 16 + quad * 4 + r;
            if (gr < NN) {
#pragma unroll
                for (int j = 0; j < 4; j++) {
                    int c = col0 + wc + j * 16 + m16;
                    h1[(size_t)gr * HID + c] = (unsigned char)(q8(acc[i][j][r], 16.f) + 128);
                }
            }
        }
    }
}

// ---------------- SpMM1: a1 = relu(A @ (h1-128)/16 + b1) ----------------
// quarter-wave rows: 4 rows per wave, 16 lanes per row, dwordx4 gathers (1 KB/instr)
// 16-deep unroll (16 KB outstanding per wave); ubyte converts + bias correction.
__global__ __launch_bounds__(256) void k_spmm1(const unsigned char* __restrict__ h1,
                                               const int2* __restrict__ cpack,
                                               const int* __restrict__ row_beg, const int* __restrict__ row_cnt,
                                               const float* __restrict__ b1, unsigned short* __restrict__ a1) {
    const int lane = threadIdx.x & 63;
    const int q = lane >> 4;           // quarter 0..3 -> row within wave
    const int t = lane & 15;           // column group: cols t*16..t*16+15
    const int row = ((int)(blockIdx.x * 256 + threadIdx.x) >> 6) * 4 + q;
    if (row >= NN) return;
    const int beg = row_beg[row];
    const int end = beg + row_cnt[row];
    float su[16];
#pragma unroll
    for (int i = 0; i < 16; i++) su[i] = 0.f;
    float sv = 0.f;
    const unsigned char* hp = h1 + t * 16;
    int e = beg;
    for (; e + 16 <= end; e += 16) {
        unsigned long long m[16];
#pragma unroll
        for (int j = 0; j < 16; j++)
            m[j] = __builtin_nontemporal_load((const unsigned long long*)(cpack + e + j));
        int4 g[16];
#pragma unroll
        for (int j = 0; j < 16; j++) {
            unsigned c = (unsigned)m[j];               // col < 2^17
            g[j] = *(const int4*)(hp + (size_t)(c << 8));
        }
#pragma unroll
        for (int j = 0; j < 16; j++) {
            const float v = __builtin_bit_cast(float, (unsigned)(m[j] >> 32)) * 0.0625f;
            sv += v;
#pragma unroll
            for (int d = 0; d < 4; d++) {
                const int r = ((const int*)&g[j])[d];
                su[d * 4 + 0] = fmaf(v, cub0(r), su[d * 4 + 0]);
                su[d * 4 + 1] = fmaf(v, cub1(r), su[d * 4 + 1]);
                su[d * 4 + 2] = fmaf(v, cub2(r), su[d * 4 + 2]);
                su[d * 4 + 3] = fmaf(v, cub3(r), su[d * 4 + 3]);
            }
        }
    }
    for (; e + 8 <= end; e += 8) {
        unsigned long long m[8];
#pragma unroll
        for (int j = 0; j < 8; j++)
            m[j] = __builtin_nontemporal_load((const unsigned long long*)(cpack + e + j));
        int4 g[8];
#pragma unroll
        for (int j = 0; j < 8; j++) {
            unsigned c = (unsigned)m[j];
            g[j] = *(const int4*)(hp + (size_t)(c << 8));
        }
#pragma unroll
        for (int j = 0; j < 8; j++) {
            const float v = __builtin_bit_cast(float, (unsigned)(m[j] >> 32)) * 0.0625f;
            sv += v;
#pragma unroll
            for (int d = 0; d < 4; d++) {
                const int r = ((const int*)&g[j])[d];
                su[d * 4 + 0] = fmaf(v, cub0(r), su[d * 4 + 0]);
                su[d * 4 + 1] = fmaf(v, cub1(r), su[d * 4 + 1]);
                su[d * 4 + 2] = fmaf(v, cub2(r), su[d * 4 + 2]);
                su[d * 4 + 3] = fmaf(v, cub3(r), su[d * 4 + 3]);
            }
        }
    }
    for (; e < end; e++) {
        int2 mm = cpack[e];
        const float v = __builtin_bit_cast(float, mm.y) * 0.0625f;
        sv += v;
        int4 gg = *(const int4*)(hp + ((size_t)(unsigned)mm.x << 8));
#pragma unroll
        for (int d = 0; d < 4; d++) {
            const int r = ((const int*)&gg)[d];
            su[d * 4 + 0] = fmaf(v, cub0(r), su[d * 4 + 0]);
            su[d * 4 + 1] = fmaf(v, cub1(r), su[d * 4 + 1]);
            su[d * 4 + 2] = fmaf(v, cub2(r), su[d * 4 + 2]);
            su[d * 4 + 3] = fmaf(v, cub3(r), su[d * 4 + 3]);
        }
    }
    const int col = t * 16;
    unsigned short o[16];
#pragma unroll
    for (int d = 0; d < 4; d++) {
        const float4 bb = *(const float4*)(b1 + col + d * 4);
        o[d * 4 + 0] = f2bfu(fmaxf(fmaf(-128.f, sv, su[d * 4 + 0]) + bb.x, 0.f));
        o[d * 4 + 1] = f2bfu(fmaxf(fmaf(-128.f, sv, su[d * 4 + 1]) + bb.y, 0.f));
        o[d * 4 + 2] = f2bfu(fmaxf(fmaf(-128.f, sv, su[d * 4 + 2]) + bb.z, 0.f));
        o[d * 4 + 3] = f2bfu(fmaxf(fmaf(-128.f, sv, su[d * 4 + 3]) + bb.w, 0.f));
    }
    unsigned short* op = a1 + (size_t)row * HID + col;
    *(short8*)op = *(short8*)o;
    *(short8*)(op + 8) = *(short8*)(o + 8);
}

// ---------------- GEMM2: h2 = u8( a1 @ W2T^T , scale 4, +128 bias ), MFMA ----------------
// block = 4 waves x 64 rows = 256 rows; N=40 padded to 48 (3 n-tiles)
__global__ __launch_bounds__(256) void k_gemm2(const unsigned short* __restrict__ a1,
                                               const unsigned short* __restrict__ W2T, unsigned char* __restrict__ h2) {
    const int tid = threadIdx.x;
    const int lane = tid & 63;
    const int w = tid >> 6;
    const int m16 = lane & 15;
    const int quad = lane >> 4;
    const int r0 = blockIdx.x * 256 + w * 64;

    f32x4 acc[4][3];
#pragma unroll
    for (int i = 0; i < 4; i++)
#pragma unroll
        for (int j = 0; j < 3; j++) acc[i][j] = (f32x4){0.f, 0.f, 0.f, 0.f};

    for (int k0 = 0; k0 < HID; k0 += 32) {
        short8 af[4], bfr[3];
#pragma unroll
        for (int i = 0; i < 4; i++) {
            int gr = r0 + i * 16 + m16;
            if (gr >= NN) gr = NN - 1;
            af[i] = *(const short8*)(a1 + (size_t)gr * HID + k0 + quad * 8);
        }
#pragma unroll
        for (int j = 0; j < 3; j++)
            bfr[j] = *(const short8*)(W2T + (size_t)(j * 16 + m16) * HID + k0 + quad * 8);
#pragma unroll
        for (int i = 0; i < 4; i++)
#pragma unroll
            for (int j = 0; j < 3; j++)
                acc[i][j] = __builtin_amdgcn_mfma_f32_16x16x32_bf16(af[i], bfr[j], acc[i][j], 0, 0, 0);
    }
#pragma unroll
    for (int i = 0; i < 4; i++) {
#pragma unroll
        for (int r = 0; r < 4; r++) {
            int gr = r0 + i * 16 + quad * 4 + r;
            if (gr < NN) {
#pragma unroll
                for (int j = 0; j < 3; j++) {
                    int c = j * 16 + m16;
                    if (c < NC) h2[(size_t)gr * 64 + c] = (unsigned char)(q8(acc[i][j][r], 4.f) + 128);
                }
            }
        }
    }
}

// ---------------- SpMM2 + bias + log_softmax ----------------
// quarter-wave rows: 4 rows per wave, 16 lanes per row, dword gathers (256 B/instr)
// 16-deep unroll; ubyte converts + bias correction.
__global__ __launch_bounds__(256) void k_spmm2(const unsigned char* __restrict__ h2,
                                               const int2* __restrict__ cpack,
                                               const int* __restrict__ row_beg, const int* __restrict__ row_cnt,
                                               const float* __restrict__ b2, float* __restrict__ out) {
    const int lane = threadIdx.x & 63;
    const int q = lane >> 4;
    const int t = lane & 15;
    const int row = ((int)(blockIdx.x * 256 + threadIdx.x) >> 6) * 4 + q;
    if (row >= NN) return;
    const bool act = t < 10;           // 10 lanes x 4 cols = NC=40
    const int off = t * 4;             // byte/col offset within padded 64 B row
    const int boff = act ? off : 0;    // clamp for b2 reads
    const int beg = row_beg[row];
    const int end = beg + row_cnt[row];
    float su[4] = {0.f, 0.f, 0.f, 0.f};
    float sv = 0.f;
    const unsigned char* hp = h2 + off;  // off <= 60, stays within 64 B padded row
    int e = beg;
    for (; e + 16 <= end; e += 16) {
        unsigned long long m[16];
#pragma unroll
        for (int j = 0; j < 16; j++)
            m[j] = __builtin_nontemporal_load((const unsigned long long*)(cpack + e + j));
        int g[16];
#pragma unroll
        for (int j = 0; j < 16; j++) {
            unsigned c = (unsigned)m[j];
            g[j] = *(const int*)(hp + (size_t)(c << 6));
        }
#pragma unroll
        for (int j = 0; j < 16; j++) {
            const float v = __builtin_bit_cast(float, (unsigned)(m[j] >> 32)) * 0.25f;
            sv += v;
            const int r = g[j];
            su[0] = fmaf(v, cub0(r), su[0]);
            su[1] = fmaf(v, cub1(r), su[1]);
            su[2] = fmaf(v, cub2(r), su[2]);
            su[3] = fmaf(v, cub3(r), su[3]);
        }
    }
    for (; e + 8 <= end; e += 8) {
        unsigned long long m[8];
#pragma unroll
        for (int j = 0; j < 8; j++)
            m[j] = __builtin_nontemporal_load((const unsigned long long*)(cpack + e + j));
        int g[8];
#pragma unroll
        for (int j = 0; j < 8; j++) {
            unsigned c = (unsigned)m[j];
            g[j] = *(const int*)(hp + (size_t)(c << 6));
        }
#pragma unroll
        for (int j = 0; j < 8; j++) {
            const float v = __builtin_bit_cast(float, (unsigned)(m[j] >> 32)) * 0.25f;
            sv += v;
            const int r = g[j];
            su[0] = fmaf(v, cub0(r), su[0]);
            su[1] = fmaf(v, cub1(r), su[1]);
            su[2] = fmaf(v, cub2(r), su[2]);
            su[3] = fmaf(v, cub3(r), su[3]);
        }
    }
    for (; e < end; e++) {
        int2 mm = cpack[e];
        const float v = __builtin_bit_cast(float, mm.y) * 0.25f;
        sv += v;
        const int r = *(const int*)(hp + ((size_t)(unsigned)mm.x << 6));
        su[0] = fmaf(v, cub0(r), su[0]);
        su[1] = fmaf(v, cub1(r), su[1]);
        su[2] = fmaf(v, cub2(r), su[2]);
        su[3] = fmaf(v, cub3(r), su[3]);
    }
    const float4 bb = *(const float4*)(b2 + boff);
    float acc[4];
    acc[0] = fmaf(-128.f, sv, su[0]) + bb.x;
    acc[1] = fmaf(-128.f, sv, su[1]) + bb.y;
    acc[2] = fmaf(-128.f, sv, su[2]) + bb.z;
    acc[3] = fmaf(-128.f, sv, su[3]) + bb.w;
    float mx = act ? fmaxf(fmaxf(acc[0], acc[1]), fmaxf(acc[2], acc[3])) : -INFINITY;
#pragma unroll
    for (int o = 1; o < 16; o <<= 1) mx = fmaxf(mx, __shfl_xor(mx, o, 16));
    float se = 0.f;
    if (act) {
#pragma unroll
        for (int i = 0; i < 4; i++) se += expf(acc[i] - mx);
    }
#pragma unroll
    for (int o = 1; o < 16; o <<= 1) se += __shfl_xor(se, o, 16);
    const float ls = logf(se);
    if (act) {
        float4 r;
        r.x = acc[0] - mx - ls;
        r.y = acc[1] - mx - ls;
        r.z = acc[2] - mx - ls;
        r.w = acc[3] - mx - ls;
        *(float4*)(out + (size_t)row * NC + off) = r;
    }
}

extern "C" void kernel_launch(void* const* d_in, const int* in_sizes, int n_in, void* d_out, int out_size,
                              void* d_ws, size_t ws_size, hipStream_t stream) {
    const float* x  = (const float*)d_in[0];
    const int*   er = (const int*)d_in[1];
    const int*   ec = (const int*)d_in[2];
    const float* ev = (const float*)d_in[3];
    const float* W1 = (const float*)d_in[4];
    const float* b1 = (const float*)d_in[5];
    const float* W2 = (const float*)d_in[6];
    const float* b2 = (const float*)d_in[7];
    float* out = (float*)d_out;
    char* ws = (char*)d_ws;

    // spack (29.6 MB) aliases h1 (25.6 MB): finecsr finishes reading spack
    // before gemm1 writes h1 (stream-ordered).
    int2*  spack       = (int2*)(ws + 0);                     // 29,628,416 B
    unsigned char* h1  = (unsigned char*)(ws + 0);            // 25,600,000 B (aliased)
    unsigned short* a1 = (unsigned short*)(ws + 29628416);    // 51,200,000 B
    unsigned char* h2  = (unsigned char*)(ws + 80828416);     //  6,400,000 B (64 B rows)
    int2*  cpack       = (int2*)(ws + 87228416);              // 29,628,416 B
    int*   row_beg     = (int*)(ws + 116856832);              // 400,000 B
    int*   row_cnt     = (int*)(ws + 117256832);              // 400,000 B
    int*   bcnt        = (int*)(ws + 117656832);              // 2,048 B
    unsigned short* W1T = (unsigned short*)(ws + 117658880);  // 262,144 B
    unsigned short* W2T = (unsigned short*)(ws + 117921024);  //  24,576 B

    hipMemsetAsync(bcnt, 0, NBUK * sizeof(int), stream);
    k_w1t<<<32, 256, 0, stream>>>(W1, W1T);
    k_w2t<<<48, 256, 0, stream>>>(W2, W2T);
    k_bin<<<BIN_BLOCKS, 256, 0, stream>>>(er, ec, ev, bcnt, spack);
    k_finecsr<<<NBUK, 256, 0, stream>>>(spack, bcnt, cpack, row_beg, row_cnt);
    k_gemm1<<<1564, 256, 0, stream>>>(x, W1T, h1);
    k_spmm1<<<(NN + 15) / 16, 256, 0, stream>>>(h1, cpack, row_beg, row_cnt, b1, a1);
    k_gemm2<<<(NN + 255) / 256, 256, 0, stream>>>(a1, W2T, h2);
    k_spmm2<<<(NN + 15) / 16, 256, 0, stream>>>(h2, cpack, row_beg, row_cnt, b2, out);
}

// Round 4
// 640.492 us; speedup vs baseline: 1.0438x; 1.0438x over previous
//
#include <hip/hip_runtime.h>
#include <math.h>

#define NN  100000
#define NE  3200000
#define FIN 512
#define HID 256
#define NC  40

#define NBUK 391                      // ceil(NN/256), bucket = row>>8
#define SPB  9472                     // fixed slots per bucket (mean 8184 + 14 sigma)
#define BIN_BLOCKS 512
#define CHUNK ((NE + BIN_BLOCKS - 1) / BIN_BLOCKS)   // 6250
#define COLMASK 0x1FFFF

typedef __attribute__((ext_vector_type(8))) short short8;
typedef __attribute__((ext_vector_type(4))) float f32x4;

__device__ inline float bf2f(unsigned short u) {
    unsigned int x = ((unsigned int)u) << 16;
    return __builtin_bit_cast(float, x);
}
__device__ inline unsigned short f2bfu(float f) {
    unsigned int x = __builtin_bit_cast(unsigned int, f);
    unsigned int r = (x + 0x7fffu + ((x >> 16) & 1u)) >> 16;
    return (unsigned short)r;
}
__device__ inline signed char q8(float v, float s) {
    int q = (int)rintf(v * s);
    q = max(-127, min(127, q));
    return (signed char)q;
}
__device__ inline unsigned cvtpk_bf16(float lo, float hi) {
    unsigned r;
    asm("v_cvt_pk_bf16_f32 %0, %1, %2" : "=v"(r) : "v"(lo), "v"(hi));
    return r;
}
// single-instruction unsigned-byte -> float converts (V_CVT_F32_UBYTE0..3)
__device__ inline float cub0(int r) { float f; asm("v_cvt_f32_ubyte0 %0, %1" : "=v"(f) : "v"(r)); return f; }
__device__ inline float cub1(int r) { float f; asm("v_cvt_f32_ubyte1 %0, %1" : "=v"(f) : "v"(r)); return f; }
__device__ inline float cub2(int r) { float f; asm("v_cvt_f32_ubyte2 %0, %1" : "=v"(f) : "v"(r)); return f; }
__device__ inline float cub3(int r) { float f; asm("v_cvt_f32_ubyte3 %0, %1" : "=v"(f) : "v"(r)); return f; }

// ---------------- bin edges into fixed-stride bucket staging (no pre-scan) ----------------
__global__ __launch_bounds__(256) void k_bin(const int* __restrict__ er, const int* __restrict__ ec,
                                             const float* __restrict__ ev, int* __restrict__ bcnt,
                                             int2* __restrict__ spack) {
    __shared__ int hist[NBUK];
    __shared__ int base[NBUK];
    __shared__ int lcur[NBUK];
    for (int i = threadIdx.x; i < NBUK; i += 256) { hist[i] = 0; lcur[i] = 0; }
    __syncthreads();
    int start = blockIdx.x * CHUNK;
    int end = min(start + CHUNK, NE);
    for (int e = start + threadIdx.x; e < end; e += 256)
        atomicAdd(&hist[er[e] >> 8], 1);
    __syncthreads();
    for (int i = threadIdx.x; i < NBUK; i += 256) {
        int h = hist[i];
        base[i] = h ? atomicAdd(&bcnt[i], h) : 0;
    }
    __syncthreads();
    for (int e = start + threadIdx.x; e < end; e += 256) {
        int r = er[e];
        int b = r >> 8;
        int ofs = atomicAdd(&lcur[b], 1);
        int2 p;
        p.x = ((r & 255) << 17) | ec[e];
        p.y = __builtin_bit_cast(int, ev[e]);
        spack[(size_t)b * SPB + base[b] + ofs] = p;
    }
}

// ---------------- fine CSR within each bucket ----------------
__global__ __launch_bounds__(256) void k_finecsr(const int2* __restrict__ spack, const int* __restrict__ bcnt,
                                                 int2* __restrict__ cpack,
                                                 int* __restrict__ row_beg, int* __restrict__ row_cnt) {
    __shared__ int cnt[256];
    __shared__ int sm[256];
    __shared__ int cur[256];
    int tid = threadIdx.x;
    int buk = blockIdx.x;
    size_t bb = (size_t)buk * SPB;
    int n = min(bcnt[buk], SPB);
    cnt[tid] = 0;
    __syncthreads();
    for (int i = tid; i < n; i += 256) {
        int lr = ((unsigned)spack[bb + i].x) >> 17;
        atomicAdd(&cnt[lr], 1);
    }
    __syncthreads();
    int v = cnt[tid];
    sm[tid] = v;
    __syncthreads();
    for (int off = 1; off < 256; off <<= 1) {
        int t = (tid >= off) ? sm[tid - off] : 0;
        __syncthreads();
        sm[tid] += t;
        __syncthreads();
    }
    int ex = sm[tid] - v;
    cur[tid] = ex;
    int grow = buk * 256 + tid;
    if (grow < NN) {
        row_beg[grow] = (int)bb + ex;
        row_cnt[grow] = v;
    }
    __syncthreads();
    for (int i = tid; i < n; i += 256) {
        int2 p = spack[bb + i];
        int lr = ((unsigned)p.x) >> 17;
        int pos = atomicAdd(&cur[lr], 1);
        int2 q;
        q.x = p.x & COLMASK;
        q.y = p.y;
        cpack[bb + pos] = q;
    }
}

// ---------------- W1 -> bf16 transposed [HID][FIN] ----------------
__global__ __launch_bounds__(256) void k_w1t(const float* __restrict__ W1, unsigned short* __restrict__ W1T) {
    int b = blockIdx.x;     // 32 blocks, 16 k each
    int n = threadIdx.x;
    unsigned short tmp[16];
#pragma unroll
    for (int kk = 0; kk < 16; kk++)
        tmp[kk] = f2bfu(W1[(size_t)(b * 16 + kk) * HID + n]);
    unsigned short* dst = W1T + (size_t)n * FIN + b * 16;
    *(short8*)dst = *(short8*)tmp;
    *(short8*)(dst + 8) = *(short8*)(tmp + 8);
}

// ---------------- W2 -> bf16 transposed [48][HID] (cols >= NC zero) ----------------
__global__ __launch_bounds__(256) void k_w2t(const float* __restrict__ W2, unsigned short* __restrict__ W2T) {
    int n = blockIdx.x;      // 0..47
    int k = threadIdx.x;     // 0..255
    float v = (n < NC) ? W2[(size_t)k * NC + n] : 0.f;
    W2T[(size_t)n * HID + k] = f2bfu(v);
}

// ---------------- GEMM1: h1 = u8( bf16(x) @ W1T , scale 16, +128 bias ) ----------------
__global__ __launch_bounds__(256) void k_gemm1(const float* __restrict__ x, const unsigned short* __restrict__ W1T,
                                               unsigned char* __restrict__ h1) {
    __shared__ unsigned short As[2][128][40];
    __shared__ unsigned short Bs[2][128][40];
    const int tid = threadIdx.x;
    const int row0 = (blockIdx.x >> 1) * 128;
    const int col0 = (blockIdx.x & 1) * 128;
    const int lane = tid & 63;
    const int w = tid >> 6;
    const int wr = (w >> 1) * 64;
    const int wc = (w & 1) * 64;
    const int m16 = lane & 15;
    const int quad = lane >> 4;

    const int srow = tid >> 1;
    const int skoff = (tid & 1) * 16;
    int gar = row0 + srow;
    if (gar >= NN) gar = NN - 1;
    const float* ax = x + (size_t)gar * FIN + skoff;
    const unsigned short* bw = W1T + (size_t)(col0 + srow) * FIN + skoff;

    f32x4 acc[4][4];
#pragma unroll
    for (int i = 0; i < 4; i++)
#pragma unroll
        for (int j = 0; j < 4; j++) acc[i][j] = (f32x4){0.f, 0.f, 0.f, 0.f};

    float4 va[4];
    uint4 vb0, vb1;

#define G1_LOAD(tt)                                                        \
    {                                                                      \
        const float* ap = ax + (tt) * 32;                                  \
        va[0] = *(const float4*)(ap);                                      \
        va[1] = *(const float4*)(ap + 4);                                  \
        va[2] = *(const float4*)(ap + 8);                                  \
        va[3] = *(const float4*)(ap + 12);                                 \
        const unsigned short* bp = bw + (tt) * 32;                         \
        vb0 = *(const uint4*)(bp);                                         \
        vb1 = *(const uint4*)(bp + 8);                                     \
    }

#define G1_STORE(bf)                                                       \
    {                                                                      \
        uint4 pa0, pa1;                                                    \
        pa0.x = cvtpk_bf16(va[0].x, va[0].y);                              \
        pa0.y = cvtpk_bf16(va[0].z, va[0].w);                              \
        pa0.z = cvtpk_bf16(va[1].x, va[1].y);                              \
        pa0.w = cvtpk_bf16(va[1].z, va[1].w);                              \
        pa1.x = cvtpk_bf16(va[2].x, va[2].y);                              \
        pa1.y = cvtpk_bf16(va[2].z, va[2].w);                              \
        pa1.z = cvtpk_bf16(va[3].x, va[3].y);                              \
        pa1.w = cvtpk_bf16(va[3].z, va[3].w);                              \
        *(uint4*)(&As[bf][srow][skoff]) = pa0;                             \
        *(uint4*)(&As[bf][srow][skoff + 8]) = pa1;                         \
        *(uint4*)(&Bs[bf][srow][skoff]) = vb0;                             \
        *(uint4*)(&Bs[bf][srow][skoff + 8]) = vb1;                         \
    }

    G1_LOAD(0)
    G1_STORE(0)
    G1_LOAD(1)
    __syncthreads();

    for (int t = 0; t < 16; ++t) {
        const int buf = t & 1;
        short8 af[4], bfr[4];
#pragma unroll
        for (int i = 0; i < 4; i++) af[i] = *(const short8*)(&As[buf][wr + i * 16 + m16][quad * 8]);
#pragma unroll
        for (int j = 0; j < 4; j++) bfr[j] = *(const short8*)(&Bs[buf][wc + j * 16 + m16][quad * 8]);
        if (t < 15) {
            G1_STORE(buf ^ 1)
            if (t < 14) G1_LOAD(t + 2)
        }
#pragma unroll
        for (int i = 0; i < 4; i++)
#pragma unroll
            for (int j = 0; j < 4; j++)
                acc[i][j] = __builtin_amdgcn_mfma_f32_16x16x32_bf16(af[i], bfr[j], acc[i][j], 0, 0, 0);
        __syncthreads();
    }
#undef G1_LOAD
#undef G1_STORE

#pragma unroll
    for (int i = 0; i < 4; i++) {
#pragma unroll
        for (int r = 0; r < 4; r++) {
            int gr = row0 + wr + i * 16 + quad * 4 + r;
            if (gr < NN) {
#pragma unroll
                for (int j = 0; j < 4; j++) {
                    int c = col0 + wc + j * 16 + m16;
                    h1[(size_t)gr * HID + c] = (unsigned char)(q8(acc[i][j][r], 16.f) + 128);
                }
            }
        }
    }
}

// ---------------- SpMM1: a1 = relu(A @ (h1-128)/16 + b1) ----------------
// WAVE PER ROW: 64 lanes x 4 cols = full 256-B row per gather instruction.
// row/beg/end wave-uniform -> cpack via scalar loads, gather = SGPR base + lane offset.
// 16 edges per chunk, all gathers independent; partial chunk masked by v=0 (no tail loop).
__global__ __launch_bounds__(256) void k_spmm1(const unsigned char* __restrict__ h1,
                                               const int2* __restrict__ cpack,
                                               const int* __restrict__ row_beg, const int* __restrict__ row_cnt,
                                               const float* __restrict__ b1, unsigned short* __restrict__ a1) {
    const int lane = threadIdx.x & 63;
    const int row = (int)__builtin_amdgcn_readfirstlane(blockIdx.x * 4 + (threadIdx.x >> 6));
    if (row >= NN) return;
    const int beg = (int)__builtin_amdgcn_readfirstlane(row_beg[row]);
    const int cnt = (int)__builtin_amdgcn_readfirstlane(row_cnt[row]);
    const int end = beg + cnt;
    const int voff = lane * 4;            // byte offset within the 256-B row (4 cols/lane)
    float su[4] = {0.f, 0.f, 0.f, 0.f};
    float sv = 0.f;

    for (int e0 = beg; e0 < end; e0 += 16) {
        unsigned cb[16];
        float vv[16];
#pragma unroll
        for (int j = 0; j < 16; j++) {
            int idx = e0 + j;
            int cl = idx < end ? idx : end - 1;     // uniform clamp
            int2 p = cpack[cl];                     // uniform -> s_load
            cb[j] = ((unsigned)p.x & COLMASK) << 8; // mask keeps address in-bounds even for dup slots
            vv[j] = idx < end ? __builtin_bit_cast(float, p.y) * 0.0625f : 0.f;
        }
        int g[16];
#pragma unroll
        for (int j = 0; j < 16; j++)
            g[j] = *(const int*)(h1 + (size_t)cb[j] + voff);
#pragma unroll
        for (int j = 0; j < 16; j++) {
            sv += vv[j];
            su[0] = fmaf(vv[j], cub0(g[j]), su[0]);
            su[1] = fmaf(vv[j], cub1(g[j]), su[1]);
            su[2] = fmaf(vv[j], cub2(g[j]), su[2]);
            su[3] = fmaf(vv[j], cub3(g[j]), su[3]);
        }
    }

    const int col = lane * 4;
    const float4 bb = *(const float4*)(b1 + col);
    ushort4 o;
    o.x = f2bfu(fmaxf(fmaf(-128.f, sv, su[0]) + bb.x, 0.f));
    o.y = f2bfu(fmaxf(fmaf(-128.f, sv, su[1]) + bb.y, 0.f));
    o.z = f2bfu(fmaxf(fmaf(-128.f, sv, su[2]) + bb.z, 0.f));
    o.w = f2bfu(fmaxf(fmaf(-128.f, sv, su[3]) + bb.w, 0.f));
    *(ushort4*)(a1 + (size_t)row * HID + col) = o;
}

// ---------------- GEMM2: h2 = u8( a1 @ W2T^T , scale 4, +128 bias ), MFMA ----------------
__global__ __launch_bounds__(256) void k_gemm2(const unsigned short* __restrict__ a1,
                                               const unsigned short* __restrict__ W2T, unsigned char* __restrict__ h2) {
    const int tid = threadIdx.x;
    const int lane = tid & 63;
    const int w = tid >> 6;
    const int m16 = lane & 15;
    const int quad = lane >> 4;
    const int r0 = blockIdx.x * 256 + w * 64;

    f32x4 acc[4][3];
#pragma unroll
    for (int i = 0; i < 4; i++)
#pragma unroll
        for (int j = 0; j < 3; j++) acc[i][j] = (f32x4){0.f, 0.f, 0.f, 0.f};

    for (int k0 = 0; k0 < HID; k0 += 32) {
        short8 af[4], bfr[3];
#pragma unroll
        for (int i = 0; i < 4; i++) {
            int gr = r0 + i * 16 + m16;
            if (gr >= NN) gr = NN - 1;
            af[i] = *(const short8*)(a1 + (size_t)gr * HID + k0 + quad * 8);
        }
#pragma unroll
        for (int j = 0; j < 3; j++)
            bfr[j] = *(const short8*)(W2T + (size_t)(j * 16 + m16) * HID + k0 + quad * 8);
#pragma unroll
        for (int i = 0; i < 4; i++)
#pragma unroll
            for (int j = 0; j < 3; j++)
                acc[i][j] = __builtin_amdgcn_mfma_f32_16x16x32_bf16(af[i], bfr[j], acc[i][j], 0, 0, 0);
    }
#pragma unroll
    for (int i = 0; i < 4; i++) {
#pragma unroll
        for (int r = 0; r < 4; r++) {
            int gr = r0 + i * 16 + quad * 4 + r;
            if (gr < NN) {
#pragma unroll
                for (int j = 0; j < 3; j++) {
                    int c = j * 16 + m16;
                    if (c < NC) h2[(size_t)gr * 64 + c] = (unsigned char)(q8(acc[i][j][r], 4.f) + 128);
                }
            }
        }
    }
}

// ---------------- SpMM2 + bias + log_softmax ----------------
// WAVE PER ROW: 4 edge-slots x 16 lanes (4 x 64 B per gather instr), 16 edges/iter,
// cross-slot shfl_xor reduction, then width-16 softmax. No tails, no divergence.
__global__ __launch_bounds__(256) void k_spmm2(const unsigned char* __restrict__ h2,
                                               const int2* __restrict__ cpack,
                                               const int* __restrict__ row_beg, const int* __restrict__ row_cnt,
                                               const float* __restrict__ b2, float* __restrict__ out) {
    const int lane = threadIdx.x & 63;
    const int slot = lane >> 4;          // edge slot 0..3
    const int t = lane & 15;             // column group: cols 4t..4t+3
    const int row = (int)__builtin_amdgcn_readfirstlane(blockIdx.x * 4 + (threadIdx.x >> 6));
    if (row >= NN) return;
    const int beg = (int)__builtin_amdgcn_readfirstlane(row_beg[row]);
    const int cnt = (int)__builtin_amdgcn_readfirstlane(row_cnt[row]);
    const int end = beg + cnt;
    const int t4 = t * 4;
    float su[4] = {0.f, 0.f, 0.f, 0.f};
    float sv = 0.f;

    for (int e0 = beg; e0 < end; e0 += 16) {
        unsigned cb[4];
        float vs[4];
#pragma unroll
        for (int u = 0; u < 4; u++) {
            int idx = e0 + u * 4 + slot;
            int cl = idx < end ? idx : end - 1;
            int2 p = cpack[cl];                       // 4 contiguous 8-B segs per slot-group
            cb[u] = ((unsigned)p.x & COLMASK) << 6;
            vs[u] = idx < end ? __builtin_bit_cast(float, p.y) * 0.25f : 0.f;
        }
        int g[4];
#pragma unroll
        for (int u = 0; u < 4; u++)
            g[u] = *(const int*)(h2 + (size_t)cb[u] + t4);
#pragma unroll
        for (int u = 0; u < 4; u++) {
            sv += vs[u];
            su[0] = fmaf(vs[u], cub0(g[u]), su[0]);
            su[1] = fmaf(vs[u], cub1(g[u]), su[1]);
            su[2] = fmaf(vs[u], cub2(g[u]), su[2]);
            su[3] = fmaf(vs[u], cub3(g[u]), su[3]);
        }
    }

    // reduce across the 4 edge-slots
#pragma unroll
    for (int i = 0; i < 4; i++) {
        su[i] += __shfl_xor(su[i], 16, 64);
        su[i] += __shfl_xor(su[i], 32, 64);
    }
    sv += __shfl_xor(sv, 16, 64);
    sv += __shfl_xor(sv, 32, 64);

    const bool act = t < 10;             // 10 lanes x 4 cols = NC=40
    const int off = t4;
    const int boff = act ? off : 0;
    const float4 bb = *(const float4*)(b2 + boff);
    float acc[4];
    acc[0] = fmaf(-128.f, sv, su[0]) + bb.x;
    acc[1] = fmaf(-128.f, sv, su[1]) + bb.y;
    acc[2] = fmaf(-128.f, sv, su[2]) + bb.z;
    acc[3] = fmaf(-128.f, sv, su[3]) + bb.w;
    float mx = act ? fmaxf(fmaxf(acc[0], acc[1]), fmaxf(acc[2], acc[3])) : -INFINITY;
#pragma unroll
    for (int o = 1; o < 16; o <<= 1) mx = fmaxf(mx, __shfl_xor(mx, o, 16));
    float se = 0.f;
    if (act) {
#pragma unroll
        for (int i = 0; i < 4; i++) se += expf(acc[i] - mx);
    }
#pragma unroll
    for (int o = 1; o < 16; o <<= 1) se += __shfl_xor(se, o, 16);
    const float ls = logf(se);
    if (act && slot == 0) {
        float4 r;
        r.x = acc[0] - mx - ls;
        r.y = acc[1] - mx - ls;
        r.z = acc[2] - mx - ls;
        r.w = acc[3] - mx - ls;
        *(float4*)(out + (size_t)row * NC + off) = r;
    }
}

extern "C" void kernel_launch(void* const* d_in, const int* in_sizes, int n_in, void* d_out, int out_size,
                              void* d_ws, size_t ws_size, hipStream_t stream) {
    const float* x  = (const float*)d_in[0];
    const int*   er = (const int*)d_in[1];
    const int*   ec = (const int*)d_in[2];
    const float* ev = (const float*)d_in[3];
    const float* W1 = (const float*)d_in[4];
    const float* b1 = (const float*)d_in[5];
    const float* W2 = (const float*)d_in[6];
    const float* b2 = (const float*)d_in[7];
    float* out = (float*)d_out;
    char* ws = (char*)d_ws;

    // spack (29.6 MB) aliases h1 (25.6 MB): finecsr finishes reading spack
    // before gemm1 writes h1 (stream-ordered).
    int2*  spack       = (int2*)(ws + 0);                     // 29,628,416 B
    unsigned char* h1  = (unsigned char*)(ws + 0);            // 25,600,000 B (aliased)
    unsigned short* a1 = (unsigned short*)(ws + 29628416);    // 51,200,000 B
    unsigned char* h2  = (unsigned char*)(ws + 80828416);     //  6,400,000 B (64 B rows)
    int2*  cpack       = (int2*)(ws + 87228416);              // 29,628,416 B
    int*   row_beg     = (int*)(ws + 116856832);              // 400,000 B
    int*   row_cnt     = (int*)(ws + 117256832);              // 400,000 B
    int*   bcnt        = (int*)(ws + 117656832);              // 2,048 B
    unsigned short* W1T = (unsigned short*)(ws + 117658880);  // 262,144 B
    unsigned short* W2T = (unsigned short*)(ws + 117921024);  //  24,576 B

    hipMemsetAsync(bcnt, 0, NBUK * sizeof(int), stream);
    k_w1t<<<32, 256, 0, stream>>>(W1, W1T);
    k_w2t<<<48, 256, 0, stream>>>(W2, W2T);
    k_bin<<<BIN_BLOCKS, 256, 0, stream>>>(er, ec, ev, bcnt, spack);
    k_finecsr<<<NBUK, 256, 0, stream>>>(spack, bcnt, cpack, row_beg, row_cnt);
    k_gemm1<<<1564, 256, 0, stream>>>(x, W1T, h1);
    k_spmm1<<<NN / 4, 256, 0, stream>>>(h1, cpack, row_beg, row_cnt, b1, a1);
    k_gemm2<<<(NN + 255) / 256, 256, 0, stream>>>(a1, W2T, h2);
    k_spmm2<<<NN / 4, 256, 0, stream>>>(h2, cpack, row_beg, row_cnt, b2, out);
}

// Round 5
// 631.899 us; speedup vs baseline: 1.0580x; 1.0136x over previous
//
#include <hip/hip_runtime.h>
#include <math.h>

#define NN  100000
#define NE  3200000
#define FIN 512
#define HID 256
#define NC  40

#define NBUK 391                      // ceil(NN/256), bucket = row>>8
#define SPB  9472                     // fixed slots per bucket (mean 8184 + 14 sigma)
#define BIN_BLOCKS 782
#define CHUNK 4096                    // 782*4096 >= NE; LDS-staged coalesced writes
#define COLMASK 0x1FFFF

typedef __attribute__((ext_vector_type(8))) short short8;
typedef __attribute__((ext_vector_type(4))) float f32x4;

__device__ inline float bf2f(unsigned short u) {
    unsigned int x = ((unsigned int)u) << 16;
    return __builtin_bit_cast(float, x);
}
__device__ inline unsigned short f2bfu(float f) {
    unsigned int x = __builtin_bit_cast(unsigned int, f);
    unsigned int r = (x + 0x7fffu + ((x >> 16) & 1u)) >> 16;
    return (unsigned short)r;
}
__device__ inline signed char q8(float v, float s) {
    int q = (int)rintf(v * s);
    q = max(-127, min(127, q));
    return (signed char)q;
}
__device__ inline unsigned cvtpk_bf16(float lo, float hi) {
    unsigned r;
    asm("v_cvt_pk_bf16_f32 %0, %1, %2" : "=v"(r) : "v"(lo), "v"(hi));
    return r;
}
// single-instruction unsigned-byte -> float converts (V_CVT_F32_UBYTE0..3)
__device__ inline float cub0(int r) { float f; asm("v_cvt_f32_ubyte0 %0, %1" : "=v"(f) : "v"(r)); return f; }
__device__ inline float cub1(int r) { float f; asm("v_cvt_f32_ubyte1 %0, %1" : "=v"(f) : "v"(r)); return f; }
__device__ inline float cub2(int r) { float f; asm("v_cvt_f32_ubyte2 %0, %1" : "=v"(f) : "v"(r)); return f; }
__device__ inline float cub3(int r) { float f; asm("v_cvt_f32_ubyte3 %0, %1" : "=v"(f) : "v"(r)); return f; }

// ---------------- bin edges: LDS-staged, bucket-grouped coalesced writes ----------------
__global__ __launch_bounds__(256) void k_bin(const int* __restrict__ er, const int* __restrict__ ec,
                                             const float* __restrict__ ev, int* __restrict__ bcnt,
                                             int2* __restrict__ spack) {
    __shared__ int hist[392];
    __shared__ int lscan[392];
    __shared__ int gbase[NBUK];
    __shared__ int lcur[NBUK];
    __shared__ int sm[256];
    __shared__ int2 ebuf[CHUNK];          // 32 KB
    __shared__ unsigned short bbuf[CHUNK]; // 8 KB
    const int tid = threadIdx.x;
    for (int i = tid; i < 392; i += 256) hist[i] = 0;
    for (int i = tid; i < NBUK; i += 256) lcur[i] = 0;
    __syncthreads();
    const int start = blockIdx.x * CHUNK;
    const int end = min(start + CHUNK, NE);
    const int n = end - start;
    for (int e = start + tid; e < end; e += 256)
        atomicAdd(&hist[er[e] >> 8], 1);
    __syncthreads();
    // exclusive scan over 392 bucket counts: thread t covers slots 2t, 2t+1
    int a = (2 * tid < 392) ? hist[2 * tid] : 0;
    int b = (2 * tid + 1 < 392) ? hist[2 * tid + 1] : 0;
    int v = a + b;
    sm[tid] = v;
    __syncthreads();
    for (int off = 1; off < 256; off <<= 1) {
        int t2 = (tid >= off) ? sm[tid - off] : 0;
        __syncthreads();
        sm[tid] += t2;
        __syncthreads();
    }
    int ex = sm[tid] - v;
    if (2 * tid < 392) lscan[2 * tid] = ex;
    if (2 * tid + 1 < 392) lscan[2 * tid + 1] = ex + a;
    for (int i = tid; i < NBUK; i += 256) {
        int h = hist[i];
        gbase[i] = h ? atomicAdd(&bcnt[i], h) : 0;
    }
    __syncthreads();
    // stage edges into LDS grouped by bucket
    for (int e = start + tid; e < end; e += 256) {
        int r = er[e];
        int bk = r >> 8;
        int lpos = atomicAdd(&lcur[bk], 1);
        int pos = lscan[bk] + lpos;
        int2 p;
        p.x = ((r & 255) << 17) | ec[e];
        p.y = __builtin_bit_cast(int, ev[e]);
        ebuf[pos] = p;
        bbuf[pos] = (unsigned short)bk;
    }
    __syncthreads();
    // linear write-out: consecutive lanes -> consecutive global addresses per bucket run
    for (int i = tid; i < n; i += 256) {
        int bk = bbuf[i];
        spack[(size_t)bk * SPB + gbase[bk] + (i - lscan[bk])] = ebuf[i];
    }
}

// ---------------- fine CSR within each bucket ----------------
__global__ __launch_bounds__(256) void k_finecsr(const int2* __restrict__ spack, const int* __restrict__ bcnt,
                                                 int2* __restrict__ cpack,
                                                 int* __restrict__ row_beg, int* __restrict__ row_cnt) {
    __shared__ int cnt[256];
    __shared__ int sm[256];
    __shared__ int cur[256];
    int tid = threadIdx.x;
    int buk = blockIdx.x;
    size_t bb = (size_t)buk * SPB;
    int n = min(bcnt[buk], SPB);
    cnt[tid] = 0;
    __syncthreads();
    for (int i = tid; i < n; i += 256) {
        int lr = ((unsigned)spack[bb + i].x) >> 17;
        atomicAdd(&cnt[lr], 1);
    }
    __syncthreads();
    int v = cnt[tid];
    sm[tid] = v;
    __syncthreads();
    for (int off = 1; off < 256; off <<= 1) {
        int t = (tid >= off) ? sm[tid - off] : 0;
        __syncthreads();
        sm[tid] += t;
        __syncthreads();
    }
    int ex = sm[tid] - v;
    cur[tid] = ex;
    int grow = buk * 256 + tid;
    if (grow < NN) {
        row_beg[grow] = (int)bb + ex;
        row_cnt[grow] = v;
    }
    __syncthreads();
    for (int i = tid; i < n; i += 256) {
        int2 p = spack[bb + i];
        int lr = ((unsigned)p.x) >> 17;
        int pos = atomicAdd(&cur[lr], 1);
        int2 q;
        q.x = p.x & COLMASK;
        q.y = p.y;
        cpack[bb + pos] = q;
    }
}

// ---------------- W1 -> bf16 transposed [HID][FIN] ----------------
__global__ __launch_bounds__(256) void k_w1t(const float* __restrict__ W1, unsigned short* __restrict__ W1T) {
    int b = blockIdx.x;     // 32 blocks, 16 k each
    int n = threadIdx.x;
    unsigned short tmp[16];
#pragma unroll
    for (int kk = 0; kk < 16; kk++)
        tmp[kk] = f2bfu(W1[(size_t)(b * 16 + kk) * HID + n]);
    unsigned short* dst = W1T + (size_t)n * FIN + b * 16;
    *(short8*)dst = *(short8*)tmp;
    *(short8*)(dst + 8) = *(short8*)(tmp + 8);
}

// ---------------- W2 -> bf16 transposed [48][HID] (cols >= NC zero) ----------------
__global__ __launch_bounds__(256) void k_w2t(const float* __restrict__ W2, unsigned short* __restrict__ W2T) {
    int n = blockIdx.x;      // 0..47
    int k = threadIdx.x;     // 0..255
    float v = (n < NC) ? W2[(size_t)k * NC + n] : 0.f;
    W2T[(size_t)n * HID + k] = f2bfu(v);
}

// ---------------- GEMM1: h1 = u8( bf16(x) @ W1T , scale 16, +128 bias ) ----------------
// BM=128 x BN=256 in ONE block (x read exactly once), 512 threads = 8 waves (2x4),
// wave 64x64 acc[4][4]. Double-buffered LDS (80 B stride), one barrier per K-step.
__global__ __launch_bounds__(512) void k_gemm1(const float* __restrict__ x, const unsigned short* __restrict__ W1T,
                                               unsigned char* __restrict__ h1) {
    __shared__ unsigned short As[2][128][40];
    __shared__ unsigned short Bs[2][256][40];
    const int tid = threadIdx.x;
    const int row0 = blockIdx.x * 128;
    const int lane = tid & 63;
    const int w = tid >> 6;          // 0..7
    const int wr = (w >> 2) * 64;    // 0 or 64
    const int wc = (w & 3) * 64;     // 0,64,128,192
    const int m16 = lane & 15;
    const int quad = lane >> 4;

    // A staging: thread covers row tid>>2, k-offset (tid&3)*8 (8 floats)
    const int arow = tid >> 2;
    const int akoff = (tid & 3) * 8;
    int gar = row0 + arow;
    if (gar >= NN) gar = NN - 1;
    const float* ax = x + (size_t)gar * FIN + akoff;
    // B staging: thread covers col tid>>1, k-offset (tid&1)*16 (16 shorts)
    const int brow = tid >> 1;
    const int bkoff = (tid & 1) * 16;
    const unsigned short* bw = W1T + (size_t)brow * FIN + bkoff;

    f32x4 acc[4][4];
#pragma unroll
    for (int i = 0; i < 4; i++)
#pragma unroll
        for (int j = 0; j < 4; j++) acc[i][j] = (f32x4){0.f, 0.f, 0.f, 0.f};

    float4 va0, va1;
    uint4 vb0, vb1;

#define G1_LOAD(tt)                                                        \
    {                                                                      \
        const float* ap = ax + (tt) * 32;                                  \
        va0 = *(const float4*)(ap);                                        \
        va1 = *(const float4*)(ap + 4);                                    \
        const unsigned short* bp = bw + (tt) * 32;                         \
        vb0 = *(const uint4*)(bp);                                         \
        vb1 = *(const uint4*)(bp + 8);                                     \
    }

#define G1_STORE(bf)                                                       \
    {                                                                      \
        uint4 pa;                                                          \
        pa.x = cvtpk_bf16(va0.x, va0.y);                                   \
        pa.y = cvtpk_bf16(va0.z, va0.w);                                   \
        pa.z = cvtpk_bf16(va1.x, va1.y);                                   \
        pa.w = cvtpk_bf16(va1.z, va1.w);                                   \
        *(uint4*)(&As[bf][arow][akoff]) = pa;                              \
        *(uint4*)(&Bs[bf][brow][bkoff]) = vb0;                             \
        *(uint4*)(&Bs[bf][brow][bkoff + 8]) = vb1;                         \
    }

    G1_LOAD(0)
    G1_STORE(0)
    G1_LOAD(1)
    __syncthreads();

    for (int t = 0; t < 16; ++t) {
        const int buf = t & 1;
        short8 af[4], bfr[4];
#pragma unroll
        for (int i = 0; i < 4; i++) af[i] = *(const short8*)(&As[buf][wr + i * 16 + m16][quad * 8]);
#pragma unroll
        for (int j = 0; j < 4; j++) bfr[j] = *(const short8*)(&Bs[buf][wc + j * 16 + m16][quad * 8]);
        if (t < 15) {
            G1_STORE(buf ^ 1)
            if (t < 14) G1_LOAD(t + 2)
        }
#pragma unroll
        for (int i = 0; i < 4; i++)
#pragma unroll
            for (int j = 0; j < 4; j++)
                acc[i][j] = __builtin_amdgcn_mfma_f32_16x16x32_bf16(af[i], bfr[j], acc[i][j], 0, 0, 0);
        __syncthreads();
    }
#undef G1_LOAD
#undef G1_STORE

    // epilogue: C/D layout col=lane&15, row=quad*4+reg; quantize to u8 = int8(scale16)+128
#pragma unroll
    for (int i = 0; i < 4; i++) {
#pragma unroll
        for (int r = 0; r < 4; r++) {
            int gr = row0 + wr + i * 16 + quad * 4 + r;
            if (gr < NN) {
#pragma unroll
                for (int j = 0; j < 4; j++) {
                    int c = wc + j * 16 + m16;
                    h1[(size_t)gr * HID + c] = (unsigned char)(q8(acc[i][j][r], 16.f) + 128);
                }
            }
        }
    }
}

// ---------------- SpMM1: a1 = relu(A @ (h1-128)/16 + b1) ----------------
// WAVE PER ROW: 64 lanes x 4 cols = full 256-B row per gather instruction.
// row/beg/end wave-uniform -> cpack via scalar loads, gather = SGPR base + lane offset.
// 16 edges per chunk, all gathers independent; partial chunk masked by v=0 (no tail loop).
__global__ __launch_bounds__(256) void k_spmm1(const unsigned char* __restrict__ h1,
                                               const int2* __restrict__ cpack,
                                               const int* __restrict__ row_beg, const int* __restrict__ row_cnt,
                                               const float* __restrict__ b1, unsigned short* __restrict__ a1) {
    const int lane = threadIdx.x & 63;
    const int row = (int)__builtin_amdgcn_readfirstlane(blockIdx.x * 4 + (threadIdx.x >> 6));
    if (row >= NN) return;
    const int beg = (int)__builtin_amdgcn_readfirstlane(row_beg[row]);
    const int cnt = (int)__builtin_amdgcn_readfirstlane(row_cnt[row]);
    const int end = beg + cnt;
    const int voff = lane * 4;            // byte offset within the 256-B row (4 cols/lane)
    float su[4] = {0.f, 0.f, 0.f, 0.f};
    float sv = 0.f;

    for (int e0 = beg; e0 < end; e0 += 16) {
        unsigned cb[16];
        float vv[16];
#pragma unroll
        for (int j = 0; j < 16; j++) {
            int idx = e0 + j;
            int cl = idx < end ? idx : end - 1;     // uniform clamp
            int2 p = cpack[cl];                     // uniform -> s_load
            cb[j] = ((unsigned)p.x & COLMASK) << 8; // mask keeps address in-bounds even for dup slots
            vv[j] = idx < end ? __builtin_bit_cast(float, p.y) * 0.0625f : 0.f;
        }
        int g[16];
#pragma unroll
        for (int j = 0; j < 16; j++)
            g[j] = *(const int*)(h1 + (size_t)cb[j] + voff);
#pragma unroll
        for (int j = 0; j < 16; j++) {
            sv += vv[j];
            su[0] = fmaf(vv[j], cub0(g[j]), su[0]);
            su[1] = fmaf(vv[j], cub1(g[j]), su[1]);
            su[2] = fmaf(vv[j], cub2(g[j]), su[2]);
            su[3] = fmaf(vv[j], cub3(g[j]), su[3]);
        }
    }

    const int col = lane * 4;
    const float4 bb = *(const float4*)(b1 + col);
    ushort4 o;
    o.x = f2bfu(fmaxf(fmaf(-128.f, sv, su[0]) + bb.x, 0.f));
    o.y = f2bfu(fmaxf(fmaf(-128.f, sv, su[1]) + bb.y, 0.f));
    o.z = f2bfu(fmaxf(fmaf(-128.f, sv, su[2]) + bb.z, 0.f));
    o.w = f2bfu(fmaxf(fmaf(-128.f, sv, su[3]) + bb.w, 0.f));
    *(ushort4*)(a1 + (size_t)row * HID + col) = o;
}

// ---------------- GEMM2: h2 = u8( a1 @ W2T^T , scale 4, +128 bias ), MFMA ----------------
__global__ __launch_bounds__(256) void k_gemm2(const unsigned short* __restrict__ a1,
                                               const unsigned short* __restrict__ W2T, unsigned char* __restrict__ h2) {
    const int tid = threadIdx.x;
    const int lane = tid & 63;
    const int w = tid >> 6;
    const int m16 = lane & 15;
    const int quad = lane >> 4;
    const int r0 = blockIdx.x * 256 + w * 64;

    f32x4 acc[4][3];
#pragma unroll
    for (int i = 0; i < 4; i++)
#pragma unroll
        for (int j = 0; j < 3; j++) acc[i][j] = (f32x4){0.f, 0.f, 0.f, 0.f};

    for (int k0 = 0; k0 < HID; k0 += 32) {
        short8 af[4], bfr[3];
#pragma unroll
        for (int i = 0; i < 4; i++) {
            int gr = r0 + i * 16 + m16;
            if (gr >= NN) gr = NN - 1;
            af[i] = *(const short8*)(a1 + (size_t)gr * HID + k0 + quad * 8);
        }
#pragma unroll
        for (int j = 0; j < 3; j++)
            bfr[j] = *(const short8*)(W2T + (size_t)(j * 16 + m16) * HID + k0 + quad * 8);
#pragma unroll
        for (int i = 0; i < 4; i++)
#pragma unroll
            for (int j = 0; j < 3; j++)
                acc[i][j] = __builtin_amdgcn_mfma_f32_16x16x32_bf16(af[i], bfr[j], acc[i][j], 0, 0, 0);
    }
#pragma unroll
    for (int i = 0; i < 4; i++) {
#pragma unroll
        for (int r = 0; r < 4; r++) {
            int gr = r0 + i * 16 + quad * 4 + r;
            if (gr < NN) {
#pragma unroll
                for (int j = 0; j < 3; j++) {
                    int c = j * 16 + m16;
                    if (c < NC) h2[(size_t)gr * 64 + c] = (unsigned char)(q8(acc[i][j][r], 4.f) + 128);
                }
            }
        }
    }
}

// ---------------- SpMM2 + bias + log_softmax ----------------
// WAVE PER ROW: 8 edge-slot groups x (4 slots x 16 lanes), 32 edges/iter,
// 8 gathers in flight; cross-slot shfl_xor reduction, then width-16 softmax.
__global__ __launch_bounds__(256) void k_spmm2(const unsigned char* __restrict__ h2,
                                               const int2* __restrict__ cpack,
                                               const int* __restrict__ row_beg, const int* __restrict__ row_cnt,
                                               const float* __restrict__ b2, float* __restrict__ out) {
    const int lane = threadIdx.x & 63;
    const int slot = lane >> 4;          // edge slot 0..3
    const int t = lane & 15;             // column group: cols 4t..4t+3
    const int row = (int)__builtin_amdgcn_readfirstlane(blockIdx.x * 4 + (threadIdx.x >> 6));
    if (row >= NN) return;
    const int beg = (int)__builtin_amdgcn_readfirstlane(row_beg[row]);
    const int cnt = (int)__builtin_amdgcn_readfirstlane(row_cnt[row]);
    const int end = beg + cnt;
    const int t4 = t * 4;
    float su[4] = {0.f, 0.f, 0.f, 0.f};
    float sv = 0.f;

    for (int e0 = beg; e0 < end; e0 += 32) {
        unsigned cb[8];
        float vs[8];
#pragma unroll
        for (int u = 0; u < 8; u++) {
            int idx = e0 + u * 4 + slot;
            int cl = idx < end ? idx : end - 1;
            int2 p = cpack[cl];
            cb[u] = ((unsigned)p.x & COLMASK) << 6;
            vs[u] = idx < end ? __builtin_bit_cast(float, p.y) * 0.25f : 0.f;
        }
        int g[8];
#pragma unroll
        for (int u = 0; u < 8; u++)
            g[u] = *(const int*)(h2 + (size_t)cb[u] + t4);
#pragma unroll
        for (int u = 0; u < 8; u++) {
            sv += vs[u];
            su[0] = fmaf(vs[u], cub0(g[u]), su[0]);
            su[1] = fmaf(vs[u], cub1(g[u]), su[1]);
            su[2] = fmaf(vs[u], cub2(g[u]), su[2]);
            su[3] = fmaf(vs[u], cub3(g[u]), su[3]);
        }
    }

    // reduce across the 4 edge-slots
#pragma unroll
    for (int i = 0; i < 4; i++) {
        su[i] += __shfl_xor(su[i], 16, 64);
        su[i] += __shfl_xor(su[i], 32, 64);
    }
    sv += __shfl_xor(sv, 16, 64);
    sv += __shfl_xor(sv, 32, 64);

    const bool act = t < 10;             // 10 lanes x 4 cols = NC=40
    const int off = t4;
    const int boff = act ? off : 0;
    const float4 bb = *(const float4*)(b2 + boff);
    float acc[4];
    acc[0] = fmaf(-128.f, sv, su[0]) + bb.x;
    acc[1] = fmaf(-128.f, sv, su[1]) + bb.y;
    acc[2] = fmaf(-128.f, sv, su[2]) + bb.z;
    acc[3] = fmaf(-128.f, sv, su[3]) + bb.w;
    float mx = act ? fmaxf(fmaxf(acc[0], acc[1]), fmaxf(acc[2], acc[3])) : -INFINITY;
#pragma unroll
    for (int o = 1; o < 16; o <<= 1) mx = fmaxf(mx, __shfl_xor(mx, o, 16));
    float se = 0.f;
    if (act) {
#pragma unroll
        for (int i = 0; i < 4; i++) se += expf(acc[i] - mx);
    }
#pragma unroll
    for (int o = 1; o < 16; o <<= 1) se += __shfl_xor(se, o, 16);
    const float ls = logf(se);
    if (act && slot == 0) {
        float4 r;
        r.x = acc[0] - mx - ls;
        r.y = acc[1] - mx - ls;
        r.z = acc[2] - mx - ls;
        r.w = acc[3] - mx - ls;
        *(float4*)(out + (size_t)row * NC + off) = r;
    }
}

extern "C" void kernel_launch(void* const* d_in, const int* in_sizes, int n_in, void* d_out, int out_size,
                              void* d_ws, size_t ws_size, hipStream_t stream) {
    const float* x  = (const float*)d_in[0];
    const int*   er = (const int*)d_in[1];
    const int*   ec = (const int*)d_in[2];
    const float* ev = (const float*)d_in[3];
    const float* W1 = (const float*)d_in[4];
    const float* b1 = (const float*)d_in[5];
    const float* W2 = (const float*)d_in[6];
    const float* b2 = (const float*)d_in[7];
    float* out = (float*)d_out;
    char* ws = (char*)d_ws;

    // spack (29.6 MB) aliases h1 (25.6 MB): finecsr finishes reading spack
    // before gemm1 writes h1 (stream-ordered).
    int2*  spack       = (int2*)(ws + 0);                     // 29,628,416 B
    unsigned char* h1  = (unsigned char*)(ws + 0);            // 25,600,000 B (aliased)
    unsigned short* a1 = (unsigned short*)(ws + 29628416);    // 51,200,000 B
    unsigned char* h2  = (unsigned char*)(ws + 80828416);     //  6,400,000 B (64 B rows)
    int2*  cpack       = (int2*)(ws + 87228416);              // 29,628,416 B
    int*   row_beg     = (int*)(ws + 116856832);              // 400,000 B
    int*   row_cnt     = (int*)(ws + 117256832);              // 400,000 B
    int*   bcnt        = (int*)(ws + 117656832);              // 2,048 B
    unsigned short* W1T = (unsigned short*)(ws + 117658880);  // 262,144 B
    unsigned short* W2T = (unsigned short*)(ws + 117921024);  //  24,576 B

    hipMemsetAsync(bcnt, 0, NBUK * sizeof(int), stream);
    k_w1t<<<32, 256, 0, stream>>>(W1, W1T);
    k_w2t<<<48, 256, 0, stream>>>(W2, W2T);
    k_bin<<<BIN_BLOCKS, 256, 0, stream>>>(er, ec, ev, bcnt, spack);
    k_finecsr<<<NBUK, 256, 0, stream>>>(spack, bcnt, cpack, row_beg, row_cnt);
    k_gemm1<<<782, 512, 0, stream>>>(x, W1T, h1);
    k_spmm1<<<NN / 4, 256, 0, stream>>>(h1, cpack, row_beg, row_cnt, b1, a1);
    k_gemm2<<<(NN + 255) / 256, 256, 0, stream>>>(a1, W2T, h2);
    k_spmm2<<<NN / 4, 256, 0, stream>>>(h2, cpack, row_beg, row_cnt, b2, out);
}

// Round 6
// 613.401 us; speedup vs baseline: 1.0899x; 1.0302x over previous
//
#include <hip/hip_runtime.h>
#include <math.h>

#define NN  100000
#define NE  3200000
#define FIN 512
#define HID 256
#define NC  40

#define NBUK 391                      // ceil(NN/256), bucket = row>>8
#define SPB  9472                     // fixed slots per bucket (mean 8184 + 14 sigma)
#define CHUNK 4096                    // bin chunk; 782*4096 >= NE
#define COLMASK 0x1FFFF

typedef __attribute__((ext_vector_type(8))) short short8;
typedef __attribute__((ext_vector_type(4))) float f32x4;

__device__ inline float bf2f(unsigned short u) {
    unsigned int x = ((unsigned int)u) << 16;
    return __builtin_bit_cast(float, x);
}
__device__ inline unsigned short f2bfu(float f) {
    unsigned int x = __builtin_bit_cast(unsigned int, f);
    unsigned int r = (x + 0x7fffu + ((x >> 16) & 1u)) >> 16;
    return (unsigned short)r;
}
__device__ inline signed char q8(float v, float s) {
    int q = (int)rintf(v * s);
    q = max(-127, min(127, q));
    return (signed char)q;
}
__device__ inline unsigned cvtpk_bf16(float lo, float hi) {
    unsigned r;
    asm("v_cvt_pk_bf16_f32 %0, %1, %2" : "=v"(r) : "v"(lo), "v"(hi));
    return r;
}
// single-instruction unsigned-byte -> float converts (V_CVT_F32_UBYTE0..3)
__device__ inline float cub0(int r) { float f; asm("v_cvt_f32_ubyte0 %0, %1" : "=v"(f) : "v"(r)); return f; }
__device__ inline float cub1(int r) { float f; asm("v_cvt_f32_ubyte1 %0, %1" : "=v"(f) : "v"(r)); return f; }
__device__ inline float cub2(int r) { float f; asm("v_cvt_f32_ubyte2 %0, %1" : "=v"(f) : "v"(r)); return f; }
__device__ inline float cub3(int r) { float f; asm("v_cvt_f32_ubyte3 %0, %1" : "=v"(f) : "v"(r)); return f; }

// ---------------- W1 -> bf16 transposed [HID][FIN] ----------------
__global__ __launch_bounds__(256) void k_w1t(const float* __restrict__ W1, unsigned short* __restrict__ W1T) {
    int b = blockIdx.x;     // 32 blocks, 16 k each
    int n = threadIdx.x;
    unsigned short tmp[16];
#pragma unroll
    for (int kk = 0; kk < 16; kk++)
        tmp[kk] = f2bfu(W1[(size_t)(b * 16 + kk) * HID + n]);
    unsigned short* dst = W1T + (size_t)n * FIN + b * 16;
    *(short8*)dst = *(short8*)tmp;
    *(short8*)(dst + 8) = *(short8*)(tmp + 8);
}

// ---------------- FUSED: gemm1 (even blocks) || bin (odd blocks) ----------------
// gemm1: h1 = u8( bf16(x) @ W1T, scale 16, +128 ), BM=128 BN=256, 8 waves 2x4,
//        double-buffered LDS, one barrier per K-step. h1 does NOT alias spack.
// bin:   LDS-staged bucket-grouped coalesced writes into spack (aliases a1, dead
//        until spmm1 which runs after finecsr).
__global__ __launch_bounds__(512) void k_fused(const float* __restrict__ x, const unsigned short* __restrict__ W1T,
                                               unsigned char* __restrict__ h1,
                                               const int* __restrict__ er, const int* __restrict__ ec,
                                               const float* __restrict__ ev, int* __restrict__ bcnt,
                                               int2* __restrict__ spack) {
    __shared__ __align__(16) char smem[61440];
    const int role = blockIdx.x & 1;
    const int gid = blockIdx.x >> 1;
    const int tid = threadIdx.x;

    if (role == 1) {
        // ---------- bin ----------
        int* hist = (int*)smem;                              // 392*4
        int* lscan = (int*)(smem + 1568);                    // 392*4
        int* gbase = (int*)(smem + 3136);                    // 391*4
        int* lcur  = (int*)(smem + 4700);                    // 391*4 (ends 6264)
        int* sm    = (int*)(smem + 6272);                    // 512*4 (ends 8320)
        int2* ebuf = (int2*)(smem + 8320);                   // 4096*8 (ends 41088)
        unsigned short* bbuf = (unsigned short*)(smem + 41088); // 4096*2 (ends 49280)
        if (tid < 392) hist[tid] = 0;
        if (tid < 391) lcur[tid] = 0;
        __syncthreads();
        const int start = gid * CHUNK;
        const int end = min(start + CHUNK, NE);
        const int n = end - start;
        for (int e = start + tid; e < end; e += 512)
            atomicAdd(&hist[er[e] >> 8], 1);
        __syncthreads();
        int v = (tid < 392) ? hist[tid] : 0;
        sm[tid] = v;
        __syncthreads();
        for (int off = 1; off < 512; off <<= 1) {
            int t2 = (tid >= off) ? sm[tid - off] : 0;
            __syncthreads();
            sm[tid] += t2;
            __syncthreads();
        }
        if (tid < 392) lscan[tid] = sm[tid] - v;
        if (tid < 391) {
            int h = hist[tid];
            gbase[tid] = h ? atomicAdd(&bcnt[tid], h) : 0;
        }
        __syncthreads();
        for (int e = start + tid; e < end; e += 512) {
            int r = er[e];
            int bk = r >> 8;
            int lpos = atomicAdd(&lcur[bk], 1);
            int pos = lscan[bk] + lpos;
            int2 p;
            p.x = ((r & 255) << 17) | ec[e];
            p.y = __builtin_bit_cast(int, ev[e]);
            ebuf[pos] = p;
            bbuf[pos] = (unsigned short)bk;
        }
        __syncthreads();
        for (int i = tid; i < n; i += 512) {
            int bk = bbuf[i];
            spack[(size_t)bk * SPB + gbase[bk] + (i - lscan[bk])] = ebuf[i];
        }
        return;
    }

    // ---------- gemm1 ----------
    typedef unsigned short AsT[128][40];
    typedef unsigned short BsT[256][40];
    AsT* As = (AsT*)smem;               // 2 x 128 x 40 x 2 B = 20480
    BsT* Bs = (BsT*)(smem + 20480);     // 2 x 256 x 40 x 2 B = 40960
    const int row0 = gid * 128;
    const int lane = tid & 63;
    const int w = tid >> 6;          // 0..7
    const int wr = (w >> 2) * 64;    // 0 or 64
    const int wc = (w & 3) * 64;     // 0,64,128,192
    const int m16 = lane & 15;
    const int quad = lane >> 4;

    const int arow = tid >> 2;
    const int akoff = (tid & 3) * 8;
    int gar = row0 + arow;
    if (gar >= NN) gar = NN - 1;
    const float* ax = x + (size_t)gar * FIN + akoff;
    const int brow = tid >> 1;
    const int bkoff = (tid & 1) * 16;
    const unsigned short* bw = W1T + (size_t)brow * FIN + bkoff;

    f32x4 acc[4][4];
#pragma unroll
    for (int i = 0; i < 4; i++)
#pragma unroll
        for (int j = 0; j < 4; j++) acc[i][j] = (f32x4){0.f, 0.f, 0.f, 0.f};

    float4 va0, va1;
    uint4 vb0, vb1;

#define G1_LOAD(tt)                                                        \
    {                                                                      \
        const float* ap = ax + (tt) * 32;                                  \
        va0 = *(const float4*)(ap);                                        \
        va1 = *(const float4*)(ap + 4);                                    \
        const unsigned short* bp = bw + (tt) * 32;                         \
        vb0 = *(const uint4*)(bp);                                         \
        vb1 = *(const uint4*)(bp + 8);                                     \
    }

#define G1_STORE(bf)                                                       \
    {                                                                      \
        uint4 pa;                                                          \
        pa.x = cvtpk_bf16(va0.x, va0.y);                                   \
        pa.y = cvtpk_bf16(va0.z, va0.w);                                   \
        pa.z = cvtpk_bf16(va1.x, va1.y);                                   \
        pa.w = cvtpk_bf16(va1.z, va1.w);                                   \
        *(uint4*)(&As[bf][arow][akoff]) = pa;                              \
        *(uint4*)(&Bs[bf][brow][bkoff]) = vb0;                             \
        *(uint4*)(&Bs[bf][brow][bkoff + 8]) = vb1;                         \
    }

    G1_LOAD(0)
    G1_STORE(0)
    G1_LOAD(1)
    __syncthreads();

    for (int t = 0; t < 16; ++t) {
        const int buf = t & 1;
        short8 af[4], bfr[4];
#pragma unroll
        for (int i = 0; i < 4; i++) af[i] = *(const short8*)(&As[buf][wr + i * 16 + m16][quad * 8]);
#pragma unroll
        for (int j = 0; j < 4; j++) bfr[j] = *(const short8*)(&Bs[buf][wc + j * 16 + m16][quad * 8]);
        if (t < 15) {
            G1_STORE(buf ^ 1)
            if (t < 14) G1_LOAD(t + 2)
        }
#pragma unroll
        for (int i = 0; i < 4; i++)
#pragma unroll
            for (int j = 0; j < 4; j++)
                acc[i][j] = __builtin_amdgcn_mfma_f32_16x16x32_bf16(af[i], bfr[j], acc[i][j], 0, 0, 0);
        __syncthreads();
    }
#undef G1_LOAD
#undef G1_STORE

#pragma unroll
    for (int i = 0; i < 4; i++) {
#pragma unroll
        for (int r = 0; r < 4; r++) {
            int gr = row0 + wr + i * 16 + quad * 4 + r;
            if (gr < NN) {
#pragma unroll
                for (int j = 0; j < 4; j++) {
                    int c = wc + j * 16 + m16;
                    h1[(size_t)gr * HID + c] = (unsigned char)(q8(acc[i][j][r], 16.f) + 128);
                }
            }
        }
    }
}

// ---------------- fine CSR within each bucket (+ W2 transpose on extra blocks) ----------------
__global__ __launch_bounds__(256) void k_finecsr(const int2* __restrict__ spack, const int* __restrict__ bcnt,
                                                 int2* __restrict__ cpack,
                                                 int* __restrict__ row_beg, int* __restrict__ row_cnt,
                                                 const float* __restrict__ W2, unsigned short* __restrict__ W2T) {
    if (blockIdx.x >= NBUK) {
        // W2 -> bf16 transposed [48][HID] (cols >= NC zero)
        int n = blockIdx.x - NBUK;   // 0..47
        int k = threadIdx.x;         // 0..255
        float v = (n < NC) ? W2[(size_t)k * NC + n] : 0.f;
        W2T[(size_t)n * HID + k] = f2bfu(v);
        return;
    }
    __shared__ int cnt[256];
    __shared__ int sm[256];
    __shared__ int cur[256];
    int tid = threadIdx.x;
    int buk = blockIdx.x;
    size_t bb = (size_t)buk * SPB;
    int n = min(bcnt[buk], SPB);
    cnt[tid] = 0;
    __syncthreads();
    for (int i = tid; i < n; i += 256) {
        int lr = ((unsigned)spack[bb + i].x) >> 17;
        atomicAdd(&cnt[lr], 1);
    }
    __syncthreads();
    int v = cnt[tid];
    sm[tid] = v;
    __syncthreads();
    for (int off = 1; off < 256; off <<= 1) {
        int t = (tid >= off) ? sm[tid - off] : 0;
        __syncthreads();
        sm[tid] += t;
        __syncthreads();
    }
    int ex = sm[tid] - v;
    cur[tid] = ex;
    int grow = buk * 256 + tid;
    if (grow < NN) {
        row_beg[grow] = (int)bb + ex;
        row_cnt[grow] = v;
    }
    __syncthreads();
    for (int i = tid; i < n; i += 256) {
        int2 p = spack[bb + i];
        int lr = ((unsigned)p.x) >> 17;
        int pos = atomicAdd(&cur[lr], 1);
        int2 q;
        q.x = p.x & COLMASK;
        q.y = p.y;
        cpack[bb + pos] = q;
    }
}

// ---------------- SpMM1: a1 = relu(A @ (h1-128)/16 + b1) ----------------
// WAVE PER ROW: 64 lanes x 4 cols = full 256-B row per gather instruction.
// cpack reads are wave-uniform and UNCLAMPED (contiguous -> s_load_dwordx8);
// over-read slots masked by v=0, addresses kept in-workspace by COLMASK.
// Scale 1/16 deferred to the epilogue.
__global__ __launch_bounds__(256) void k_spmm1(const unsigned char* __restrict__ h1,
                                               const int2* __restrict__ cpack,
                                               const int* __restrict__ row_beg, const int* __restrict__ row_cnt,
                                               const float* __restrict__ b1, unsigned short* __restrict__ a1) {
    const int lane = threadIdx.x & 63;
    const int row = (int)__builtin_amdgcn_readfirstlane(blockIdx.x * 4 + (threadIdx.x >> 6));
    if (row >= NN) return;
    const int beg = (int)__builtin_amdgcn_readfirstlane(row_beg[row]);
    const int cnt = (int)__builtin_amdgcn_readfirstlane(row_cnt[row]);
    const int end = beg + cnt;
    const int voff = lane * 4;            // byte offset within the 256-B row (4 cols/lane)
    float su[4] = {0.f, 0.f, 0.f, 0.f};
    float sv = 0.f;

    for (int e0 = beg; e0 < end; e0 += 16) {
        int2 p[16];
#pragma unroll
        for (int j = 0; j < 16; j++)
            p[j] = cpack[e0 + j];                   // uniform, contiguous -> s_load_dwordx8
        unsigned cb[16];
        float vv[16];
#pragma unroll
        for (int j = 0; j < 16; j++) {
            cb[j] = ((unsigned)p[j].x & COLMASK) << 8;
            vv[j] = (e0 + j) < end ? __builtin_bit_cast(float, p[j].y) : 0.f;
        }
        int g[16];
#pragma unroll
        for (int j = 0; j < 16; j++)
            g[j] = *(const int*)(h1 + (size_t)cb[j] + voff);
#pragma unroll
        for (int j = 0; j < 16; j++) {
            sv += vv[j];
            su[0] = fmaf(vv[j], cub0(g[j]), su[0]);
            su[1] = fmaf(vv[j], cub1(g[j]), su[1]);
            su[2] = fmaf(vv[j], cub2(g[j]), su[2]);
            su[3] = fmaf(vv[j], cub3(g[j]), su[3]);
        }
    }

    const int col = lane * 4;
    const float4 bb = *(const float4*)(b1 + col);
    ushort4 o;
    o.x = f2bfu(fmaxf(fmaf(0.0625f, fmaf(-128.f, sv, su[0]), bb.x), 0.f));
    o.y = f2bfu(fmaxf(fmaf(0.0625f, fmaf(-128.f, sv, su[1]), bb.y), 0.f));
    o.z = f2bfu(fmaxf(fmaf(0.0625f, fmaf(-128.f, sv, su[2]), bb.z), 0.f));
    o.w = f2bfu(fmaxf(fmaf(0.0625f, fmaf(-128.f, sv, su[3]), bb.w), 0.f));
    *(ushort4*)(a1 + (size_t)row * HID + col) = o;
}

// ---------------- GEMM2: h2 = u8( a1 @ W2T^T , scale 4, +128 bias ), MFMA ----------------
__global__ __launch_bounds__(256) void k_gemm2(const unsigned short* __restrict__ a1,
                                               const unsigned short* __restrict__ W2T, unsigned char* __restrict__ h2) {
    const int tid = threadIdx.x;
    const int lane = tid & 63;
    const int w = tid >> 6;
    const int m16 = lane & 15;
    const int quad = lane >> 4;
    const int r0 = blockIdx.x * 256 + w * 64;

    f32x4 acc[4][3];
#pragma unroll
    for (int i = 0; i < 4; i++)
#pragma unroll
        for (int j = 0; j < 3; j++) acc[i][j] = (f32x4){0.f, 0.f, 0.f, 0.f};

    for (int k0 = 0; k0 < HID; k0 += 32) {
        short8 af[4], bfr[3];
#pragma unroll
        for (int i = 0; i < 4; i++) {
            int gr = r0 + i * 16 + m16;
            if (gr >= NN) gr = NN - 1;
            af[i] = *(const short8*)(a1 + (size_t)gr * HID + k0 + quad * 8);
        }
#pragma unroll
        for (int j = 0; j < 3; j++)
            bfr[j] = *(const short8*)(W2T + (size_t)(j * 16 + m16) * HID + k0 + quad * 8);
#pragma unroll
        for (int i = 0; i < 4; i++)
#pragma unroll
            for (int j = 0; j < 3; j++)
                acc[i][j] = __builtin_amdgcn_mfma_f32_16x16x32_bf16(af[i], bfr[j], acc[i][j], 0, 0, 0);
    }
#pragma unroll
    for (int i = 0; i < 4; i++) {
#pragma unroll
        for (int r = 0; r < 4; r++) {
            int gr = r0 + i * 16 + quad * 4 + r;
            if (gr < NN) {
#pragma unroll
                for (int j = 0; j < 3; j++) {
                    int c = j * 16 + m16;
                    if (c < NC) h2[(size_t)gr * 64 + c] = (unsigned char)(q8(acc[i][j][r], 4.f) + 128);
                }
            }
        }
    }
}

// ---------------- SpMM2 + bias + log_softmax ----------------
// WAVE PER ROW: 8 edge-slot groups x (4 slots x 16 lanes), 32 edges/iter,
// unclamped metadata reads (masked), scale 1/4 deferred to epilogue.
__global__ __launch_bounds__(256) void k_spmm2(const unsigned char* __restrict__ h2,
                                               const int2* __restrict__ cpack,
                                               const int* __restrict__ row_beg, const int* __restrict__ row_cnt,
                                               const float* __restrict__ b2, float* __restrict__ out) {
    const int lane = threadIdx.x & 63;
    const int slot = lane >> 4;          // edge slot 0..3
    const int t = lane & 15;             // column group: cols 4t..4t+3
    const int row = (int)__builtin_amdgcn_readfirstlane(blockIdx.x * 4 + (threadIdx.x >> 6));
    if (row >= NN) return;
    const int beg = (int)__builtin_amdgcn_readfirstlane(row_beg[row]);
    const int cnt = (int)__builtin_amdgcn_readfirstlane(row_cnt[row]);
    const int end = beg + cnt;
    const int t4 = t * 4;
    float su[4] = {0.f, 0.f, 0.f, 0.f};
    float sv = 0.f;

    for (int e0 = beg; e0 < end; e0 += 32) {
        unsigned cb[8];
        float vs[8];
#pragma unroll
        for (int u = 0; u < 8; u++) {
            int idx = e0 + u * 4 + slot;
            int2 p = cpack[idx];
            cb[u] = ((unsigned)p.x & COLMASK) << 6;
            vs[u] = idx < end ? __builtin_bit_cast(float, p.y) : 0.f;
        }
        int g[8];
#pragma unroll
        for (int u = 0; u < 8; u++)
            g[u] = *(const int*)(h2 + (size_t)cb[u] + t4);
#pragma unroll
        for (int u = 0; u < 8; u++) {
            sv += vs[u];
            su[0] = fmaf(vs[u], cub0(g[u]), su[0]);
            su[1] = fmaf(vs[u], cub1(g[u]), su[1]);
            su[2] = fmaf(vs[u], cub2(g[u]), su[2]);
            su[3] = fmaf(vs[u], cub3(g[u]), su[3]);
        }
    }

    // reduce across the 4 edge-slots
#pragma unroll
    for (int i = 0; i < 4; i++) {
        su[i] += __shfl_xor(su[i], 16, 64);
        su[i] += __shfl_xor(su[i], 32, 64);
    }
    sv += __shfl_xor(sv, 16, 64);
    sv += __shfl_xor(sv, 32, 64);

    const bool act = t < 10;             // 10 lanes x 4 cols = NC=40
    const int off = t4;
    const int boff = act ? off : 0;
    const float4 bb = *(const float4*)(b2 + boff);
    float acc[4];
    acc[0] = fmaf(0.25f, fmaf(-128.f, sv, su[0]), bb.x);
    acc[1] = fmaf(0.25f, fmaf(-128.f, sv, su[1]), bb.y);
    acc[2] = fmaf(0.25f, fmaf(-128.f, sv, su[2]), bb.z);
    acc[3] = fmaf(0.25f, fmaf(-128.f, sv, su[3]), bb.w);
    float mx = act ? fmaxf(fmaxf(acc[0], acc[1]), fmaxf(acc[2], acc[3])) : -INFINITY;
#pragma unroll
    for (int o = 1; o < 16; o <<= 1) mx = fmaxf(mx, __shfl_xor(mx, o, 16));
    float se = 0.f;
    if (act) {
#pragma unroll
        for (int i = 0; i < 4; i++) se += expf(acc[i] - mx);
    }
#pragma unroll
    for (int o = 1; o < 16; o <<= 1) se += __shfl_xor(se, o, 16);
    const float ls = logf(se);
    if (act && slot == 0) {
        float4 r;
        r.x = acc[0] - mx - ls;
        r.y = acc[1] - mx - ls;
        r.z = acc[2] - mx - ls;
        r.w = acc[3] - mx - ls;
        *(float4*)(out + (size_t)row * NC + off) = r;
    }
}

extern "C" void kernel_launch(void* const* d_in, const int* in_sizes, int n_in, void* d_out, int out_size,
                              void* d_ws, size_t ws_size, hipStream_t stream) {
    const float* x  = (const float*)d_in[0];
    const int*   er = (const int*)d_in[1];
    const int*   ec = (const int*)d_in[2];
    const float* ev = (const float*)d_in[3];
    const float* W1 = (const float*)d_in[4];
    const float* b1 = (const float*)d_in[5];
    const float* W2 = (const float*)d_in[6];
    const float* b2 = (const float*)d_in[7];
    float* out = (float*)d_out;
    char* ws = (char*)d_ws;

    // spack (29.6 MB) aliases a1 (51.2 MB): finecsr finishes reading spack
    // before spmm1 writes a1 (stream-ordered). h1 is now DISJOINT from spack
    // so gemm1 and bin can run concurrently in k_fused.
    int2*  spack       = (int2*)(ws + 0);                     // 29,628,416 B (within a1)
    unsigned short* a1 = (unsigned short*)(ws + 0);           // 51,200,000 B
    unsigned char* h1  = (unsigned char*)(ws + 51200000);     // 25,600,000 B
    unsigned char* h2  = (unsigned char*)(ws + 76800000);     //  6,400,000 B (64 B rows)
    int2*  cpack       = (int2*)(ws + 83200000);              // 29,628,416 B
    int*   row_beg     = (int*)(ws + 112828416);              // 400,000 B
    int*   row_cnt     = (int*)(ws + 113228416);              // 400,000 B
    int*   bcnt        = (int*)(ws + 113628416);              // 2,048 B
    unsigned short* W1T = (unsigned short*)(ws + 113630464);  // 262,144 B
    unsigned short* W2T = (unsigned short*)(ws + 113892608);  //  24,576 B

    hipMemsetAsync(bcnt, 0, NBUK * sizeof(int), stream);
    k_w1t<<<32, 256, 0, stream>>>(W1, W1T);
    k_fused<<<1564, 512, 0, stream>>>(x, W1T, h1, er, ec, ev, bcnt, spack);
    k_finecsr<<<NBUK + 48, 256, 0, stream>>>(spack, bcnt, cpack, row_beg, row_cnt, W2, W2T);
    k_spmm1<<<NN / 4, 256, 0, stream>>>(h1, cpack, row_beg, row_cnt, b1, a1);
    k_gemm2<<<(NN + 255) / 256, 256, 0, stream>>>(a1, W2T, h2);
    k_spmm2<<<NN / 4, 256, 0, stream>>>(h2, cpack, row_beg, row_cnt, b2, out);
}